// Round 5
// baseline (298.717 us; speedup 1.0000x reference)
//
#include <hip/hip_runtime.h>
#include <stdint.h>

using f32x4   = __attribute__((ext_vector_type(4))) float;
using short8  = __attribute__((ext_vector_type(8))) short;
using float4v = __attribute__((ext_vector_type(4))) float;
using float2v = __attribute__((ext_vector_type(2))) float;
using uint2v  = __attribute__((ext_vector_type(2))) unsigned int;

#define NCOL 11008
#define KDIM 4096
#define LSTRIDE 264   // LDS bytes per k-row: 128 cols * 2B + 8B pad (2-way reads)

__device__ __forceinline__ unsigned pk_bf16(float a, float b) {
  unsigned ua = __float_as_uint(a); ua += 0x7fffu + ((ua >> 16) & 1u);  // RNE
  unsigned ub = __float_as_uint(b); ub += 0x7fffu + ((ub >> 16) & 1u);
  return (ua >> 16) | (ub & 0xffff0000u);
}

// ---------------- mask kernel (fp64-exact block means over fp32 x) ----------
// grid 32 = 8 row-blocks x 4 kb-groups (16 kbs each), 256 threads.
// mask16[rb*4+grp] bit i  <->  kb = grp*16 + i active.
__global__ __launch_bounds__(256) void mask_kernel(const float* __restrict__ x,
                                                   unsigned* __restrict__ mask16) {
  const int rb  = blockIdx.x >> 2;
  const int grp = blockIdx.x & 3;
  const int t   = threadIdx.x;
  __shared__ double part[256];
  double s = 0.0;
  // iter i = row i; thread t covers cols grp*1024 + t*4 .. +3  (kb-local = t>>4)
#pragma unroll 4
  for (int i = 0; i < 16; ++i) {
    const float* p = x + (size_t)(rb * 16 + i) * KDIM + grp * 1024 + t * 4;
    float4v a = *(const float4v*)p;
    s += (double)fabsf(a[0]) + (double)fabsf(a[1]) +
         (double)fabsf(a[2]) + (double)fabsf(a[3]);
  }
  part[t] = s;
  __syncthreads();
  if (t < 16) {                      // t = local kb index
    double acc = 0.0;
#pragma unroll
    for (int u = 0; u < 16; ++u) acc += part[t * 16 + u];
    bool on = (acc * (1.0 / 1024.0)) > (double)0.8f;   // fp32 literal, as ref
    unsigned long long bal = __ballot(on);             // lanes >=16 masked off
    if (t == 0) mask16[blockIdx.x] = (unsigned)(bal & 0xffffu);
  }
}

// ---------------- GEMM: fp32 in, bf16 MFMA, fp32 out ----------------
// grid (8, 86): blockIdx.x = rb (fastest -> 8 rb of one col-tile co-resident,
// W slab shared via L2/L3), blockIdx.y -> 128-col tile. 256 threads, 4 waves.
// LDS W slab bf16 [k=64][n=128], addr = k*LSTRIDE + n*2.
// Wave wv owns cols [wv*32, wv*32+32) as even/odd column fragments.
__global__ __launch_bounds__(256) void gemm_kernel(
    const float* __restrict__ x, const float* __restrict__ w,
    const float* __restrict__ bias, const unsigned* __restrict__ mask16,
    float* __restrict__ out) {

  __shared__ __align__(16) uint8_t lds[64 * LSTRIDE];

  const int tid  = threadIdx.x;
  const int lane = tid & 63;
  const int wv   = tid >> 6;
  const int c    = lane & 15;
  const int q    = lane >> 4;
  const int rb   = blockIdx.x;
  const int n0   = blockIdx.y * 128;

  unsigned long long bm = 0;
#pragma unroll
  for (int g = 0; g < 4; ++g)
    bm |= ((unsigned long long)mask16[rb * 4 + g]) << (16 * g);

  f32x4 acc[2] = {};                 // even / odd column fragments

  // staging: thread t -> k = r*8 + (t>>5), n = (t&31)*4  (fp32 float4 load)
  const int sk = tid >> 5;
  const int sn = (tid & 31) * 4;
  uint8_t* wS = lds + (size_t)sk * LSTRIDE + sn * 2;

  for (int kb = 0; kb < 64; ++kb) {
    if (!((bm >> kb) & 1ull)) continue;        // block-uniform skip

    const float* wp = w + (size_t)(kb * 64 + sk) * NCOL + n0 + sn;
    float4v wr[8];
#pragma unroll
    for (int r = 0; r < 8; ++r)
      wr[r] = *(const float4v*)(wp + (size_t)r * 8 * NCOL);

    __syncthreads();                           // prior compute done with LDS
#pragma unroll
    for (int r = 0; r < 8; ++r) {
      uint2v v;
      v[0] = pk_bf16(wr[r][0], wr[r][1]);
      v[1] = pk_bf16(wr[r][2], wr[r][3]);
      *(uint2v*)(wS + (size_t)r * 8 * LSTRIDE) = v;
    }
    __syncthreads();

#pragma unroll
    for (int ks = 0; ks < 2; ++ks) {
      // A fragment: x[m = rb*16+c][k = kb*64 + ks*32 + q*8 + j], fp32 -> bf16
      const float* xp = x + (size_t)(rb * 16 + c) * KDIM + kb * 64 + ks * 32 + q * 8;
      float4v xa = *(const float4v*)xp;
      float4v xb = *(const float4v*)(xp + 4);
      union { short8 v; unsigned u[4]; } af;
      af.u[0] = pk_bf16(xa[0], xa[1]);
      af.u[1] = pk_bf16(xa[2], xa[3]);
      af.u[2] = pk_bf16(xb[0], xb[1]);
      af.u[3] = pk_bf16(xb[2], xb[3]);

      // B fragments: dword j = cols (2c, 2c+1) at k = ks*32 + q*8 + j
      const uint8_t* wb = lds + (size_t)(ks * 32 + q * 8) * LSTRIDE + (wv * 32 + 2 * c) * 2;
      unsigned wj[8];
#pragma unroll
      for (int j = 0; j < 8; ++j)
        wj[j] = *(const unsigned*)(wb + (size_t)j * LSTRIDE);
      union { short8 v; unsigned u[4]; } be, bo;
#pragma unroll
      for (int p = 0; p < 4; ++p) {
        be.u[p] = (wj[2 * p] & 0x0000ffffu) | (wj[2 * p + 1] << 16);   // even col
        bo.u[p] = (wj[2 * p] >> 16) | (wj[2 * p + 1] & 0xffff0000u);   // odd col
      }
      acc[0] = __builtin_amdgcn_mfma_f32_16x16x32_bf16(af.v, be.v, acc[0], 0, 0, 0);
      acc[1] = __builtin_amdgcn_mfma_f32_16x16x32_bf16(af.v, bo.v, acc[1], 0, 0, 0);
    }
  }

  // epilogue: D row = q*4+p, tile-col = c -> actual cols (2c, 2c+1); fp32 out
  const int colE = n0 + wv * 32 + 2 * c;
  const float bE = bias[colE];
  const float bO = bias[colE + 1];
#pragma unroll
  for (int p = 0; p < 4; ++p) {
    const int row = rb * 16 + q * 4 + p;
    float2v st;
    st[0] = acc[0][p] + bE;
    st[1] = acc[1][p] + bO;
    *(float2v*)(out + (size_t)row * NCOL + colE) = st;   // 8B-aligned
  }
}

extern "C" void kernel_launch(void* const* d_in, const int* in_sizes, int n_in,
                              void* d_out, int out_size, void* d_ws, size_t ws_size,
                              hipStream_t stream) {
  const float* x    = (const float*)d_in[0];
  const float* w    = (const float*)d_in[1];
  const float* bias = (const float*)d_in[2];
  float* out        = (float*)d_out;
  unsigned* mask16  = (unsigned*)d_ws;   // 32 words

  hipLaunchKernelGGL(mask_kernel, dim3(32), dim3(256), 0, stream, x, mask16);
  hipLaunchKernelGGL(gemm_kernel, dim3(8, 86), dim3(256), 0, stream,
                     x, w, bias, mask16, out);
}